// Round 3
// baseline (105.823 us; speedup 1.0000x reference)
//
#include <hip/hip_runtime.h>
#include <hip/hip_bf16.h>
#include <cmath>

typedef __attribute__((ext_vector_type(8))) short short8;
typedef __attribute__((ext_vector_type(4))) float f32x4;

#define EPS_F 1e-7f
#define NEG_DIAG_F -10.0f

__device__ __forceinline__ unsigned enc_f32(float f) {
    unsigned u = __float_as_uint(f);
    return (u & 0x80000000u) ? ~u : (u | 0x80000000u);
}
__device__ __forceinline__ float dec_f32(unsigned u) {
    return (u & 0x80000000u) ? __uint_as_float(u ^ 0x80000000u) : __uint_as_float(~u);
}

__device__ __forceinline__ void gload_lds16(const void* gptr, void* ldsptr) {
    __builtin_amdgcn_global_load_lds(
        (const __attribute__((address_space(1))) unsigned int*)gptr,
        (__attribute__((address_space(3))) unsigned int*)ldsptr,
        16, 0, 0);
}

// ---------------------------------------------------------------------------
// Kernel 1: row L2-normalize feat_k / feat_g (in f32), cast to bf16,
// zero the row-max array. One block (D=256 threads) per row.
// ---------------------------------------------------------------------------
__global__ void norm_cast_kernel(const float* __restrict__ fk, const float* __restrict__ fg,
                                 __hip_bfloat16* __restrict__ fkb, __hip_bfloat16* __restrict__ fgb,
                                 unsigned* __restrict__ rowmax, int N, int D) {
    int n = blockIdx.x;
    int t = threadIdx.x;
    float xk = fk[(size_t)n * D + t];
    float xg = fg[(size_t)n * D + t];
    float sk = xk * xk, sg = xg * xg;
#pragma unroll
    for (int off = 32; off > 0; off >>= 1) {
        sk += __shfl_xor(sk, off, 64);
        sg += __shfl_xor(sg, off, 64);
    }
    __shared__ float lsk[4], lsg[4];
    int w = t >> 6, l = t & 63;
    if (l == 0) { lsk[w] = sk; lsg[w] = sg; }
    __syncthreads();
    sk = lsk[0] + lsk[1] + lsk[2] + lsk[3];
    sg = lsg[0] + lsg[1] + lsg[2] + lsg[3];
    float rkv = 1.0f / (sqrtf(sk) + EPS_F);
    float rgv = 1.0f / (sqrtf(sg) + EPS_F);
    fkb[(size_t)n * D + t] = __float2bfloat16(xk * rkv);
    fgb[(size_t)n * D + t] = __float2bfloat16(xg * rgv);
    if (t == 0) rowmax[n] = 0u;
}

// ---------------------------------------------------------------------------
// Kernel 2: fused dual Gram GEMM (bf16 MFMA), double-buffered BK=32.
// s = (dk+1+eps)/(dg+1+eps), diag=-10, write s, atomicMax encoded row max.
// Tile 128x128, 8 waves (2x4), 2 x 32KB LDS, 2-way-free swizzle (64B rows).
// ---------------------------------------------------------------------------
#define BM 128
#define BN 128
#define BK 32
#define NTHREADS 512
#define TILE_B (BM * BK * 2)      // 8192 bytes per tile
#define BUF_B  (4 * TILE_B)       // 32768 bytes per buffer

__global__ __launch_bounds__(NTHREADS) void dual_gram_kernel(
    const __hip_bfloat16* __restrict__ fkb, const __hip_bfloat16* __restrict__ fgb,
    float* __restrict__ out, unsigned* __restrict__ rowmax, int N, int D) {

    __shared__ __align__(16) char smem[2 * BUF_B];

    int t = threadIdx.x;
    int ntiles = N / BN;
    int nwg = ntiles * ntiles;
    // XCD-aware bijective swizzle (nwg % 8 == 0)
    int bid = (blockIdx.x & 7) * (nwg >> 3) + (blockIdx.x >> 3);
    int by = bid / ntiles, bx = bid % ntiles;
    int r0 = by * BM, c0 = bx * BN;

    int w = t >> 6, l = t & 63;
    int wr = w >> 2, wc = w & 3;   // 2 x 4 wave grid; wave tile = 64 rows x 32 cols
    int lr = l & 15, lg = l >> 4;

    // --- staging addresses (per thread): row = t>>2, slot = t&3, swizzled src
    int srow = t >> 2;
    int sslot = t & 3;
    int scsb = ((sslot ^ ((srow >> 1) & 3)) << 4);   // swizzled byte col in 64B window
    const size_t rowbytes = (size_t)D * 2;
    size_t gA = (size_t)(r0 + srow) * rowbytes + scsb;  // + kbyte later
    size_t gB = (size_t)(c0 + srow) * rowbytes + scsb;
    int ldst = t << 4;                                   // linear dest in tile

    // --- LDS read offsets (per thread), swizzle folded in
    int aoff[4], boff[2];
#pragma unroll
    for (int m = 0; m < 4; ++m) {
        int row = wr * 64 + m * 16 + lr;
        aoff[m] = row * 64 + (((lg ^ ((row >> 1) & 3))) << 4);
    }
#pragma unroll
    for (int n = 0; n < 2; ++n) {
        int row = wc * 32 + n * 16 + lr;
        boff[n] = row * 64 + (((lg ^ ((row >> 1) & 3))) << 4);
    }

    f32x4 acck[4][2], accg[4][2];
    f32x4 zero = {0.f, 0.f, 0.f, 0.f};
#pragma unroll
    for (int m = 0; m < 4; ++m)
#pragma unroll
        for (int n = 0; n < 2; ++n) { acck[m][n] = zero; accg[m][n] = zero; }

    int ksteps = D / BK;

    // prologue: stage k-step 0 into buffer 0
    {
        gload_lds16((const char*)fkb + gA, smem + 0 * TILE_B + ldst);
        gload_lds16((const char*)fkb + gB, smem + 1 * TILE_B + ldst);
        gload_lds16((const char*)fgb + gA, smem + 2 * TILE_B + ldst);
        gload_lds16((const char*)fgb + gB, smem + 3 * TILE_B + ldst);
    }
    __syncthreads();

    for (int ks = 0; ks < ksteps; ++ks) {
        int cur = ks & 1;
        // issue next-tile staging into the other buffer (overlaps compute)
        if (ks + 1 < ksteps) {
            size_t kb = (size_t)(ks + 1) * (BK * 2);
            char* dst = smem + (cur ^ 1) * BUF_B + ldst;
            gload_lds16((const char*)fkb + gA + kb, dst + 0 * TILE_B);
            gload_lds16((const char*)fkb + gB + kb, dst + 1 * TILE_B);
            gload_lds16((const char*)fgb + gA + kb, dst + 2 * TILE_B);
            gload_lds16((const char*)fgb + gB + kb, dst + 3 * TILE_B);
        }
        // compute current buffer
        const char* base = smem + cur * BUF_B;
        short8 ak[4], ag[4], bk2[2], bg2[2];
#pragma unroll
        for (int m = 0; m < 4; ++m) {
            ak[m] = *(const short8*)(base + 0 * TILE_B + aoff[m]);
            ag[m] = *(const short8*)(base + 2 * TILE_B + aoff[m]);
        }
#pragma unroll
        for (int n = 0; n < 2; ++n) {
            bk2[n] = *(const short8*)(base + 1 * TILE_B + boff[n]);
            bg2[n] = *(const short8*)(base + 3 * TILE_B + boff[n]);
        }
        __builtin_amdgcn_s_setprio(1);
#pragma unroll
        for (int m = 0; m < 4; ++m)
#pragma unroll
            for (int n = 0; n < 2; ++n) {
                acck[m][n] = __builtin_amdgcn_mfma_f32_16x16x32_bf16(ak[m], bk2[n], acck[m][n], 0, 0, 0);
                accg[m][n] = __builtin_amdgcn_mfma_f32_16x16x32_bf16(ag[m], bg2[n], accg[m][n], 0, 0, 0);
            }
        __builtin_amdgcn_s_setprio(0);
        // barrier: drains this iter's stage (vmcnt) and compute reads (lgkm)
        __syncthreads();
    }

    // --- epilogue: ratio, diag, store, row max ---
    int gcoln[2];
#pragma unroll
    for (int n = 0; n < 2; ++n) gcoln[n] = c0 + wc * 32 + n * 16 + lr;

#pragma unroll
    for (int m = 0; m < 4; ++m) {
#pragma unroll
        for (int j = 0; j < 4; ++j) {
            int grow = r0 + wr * 64 + m * 16 + lg * 4 + j;   // C/D: row=(l>>4)*4+reg
            float pm = NEG_DIAG_F;
#pragma unroll
            for (int n = 0; n < 2; ++n) {
                float dk = acck[m][n][j];
                float dg = accg[m][n][j];
                float s = (dk + 1.0f + EPS_F) * __builtin_amdgcn_rcpf(dg + 1.0f + EPS_F);
                if (grow == gcoln[n]) s = NEG_DIAG_F;
                out[(size_t)grow * N + gcoln[n]] = s;
                pm = fmaxf(pm, s);
            }
#pragma unroll
            for (int off = 1; off < 16; off <<= 1)
                pm = fmaxf(pm, __shfl_xor(pm, off, 64));
            if (lr == 0) atomicMax(&rowmax[grow], enc_f32(pm));
        }
    }
}

// ---------------------------------------------------------------------------
// Kernel 3: out = exp(s - rowmax[row]) in place, float4 grid-stride.
// ---------------------------------------------------------------------------
__global__ void finalize_kernel(float* __restrict__ out, const unsigned* __restrict__ rowmax, int N) {
    size_t total = (size_t)N * N / 4;
    int cols4 = N >> 2;                       // power of two
    int sh = 31 - __clz(cols4);               // row = i >> sh
    size_t stride = (size_t)gridDim.x * blockDim.x;
    for (size_t i = (size_t)blockIdx.x * blockDim.x + threadIdx.x; i < total; i += stride) {
        float4 v = reinterpret_cast<float4*>(out)[i];
        int row = (int)(i >> sh);
        float m = dec_f32(rowmax[row]);
        v.x = __expf(v.x - m);
        v.y = __expf(v.y - m);
        v.z = __expf(v.z - m);
        v.w = __expf(v.w - m);
        reinterpret_cast<float4*>(out)[i] = v;
    }
}

// ---------------------------------------------------------------------------
extern "C" void kernel_launch(void* const* d_in, const int* in_sizes, int n_in,
                              void* d_out, int out_size, void* d_ws, size_t ws_size,
                              hipStream_t stream) {
    const float* fk = (const float*)d_in[1];
    const float* fg = (const float*)d_in[2];
    float* out = (float*)d_out;

    int N = (int)llround(sqrt((double)out_size));   // 4096
    int D = in_sizes[1] / N;                        // 256

    char* ws = (char*)d_ws;
    __hip_bfloat16* fkb = (__hip_bfloat16*)ws;
    __hip_bfloat16* fgb = (__hip_bfloat16*)(ws + (size_t)N * D * 2);
    unsigned* rowmax = (unsigned*)(ws + (size_t)N * D * 4);

    norm_cast_kernel<<<N, D, 0, stream>>>(fk, fg, fkb, fgb, rowmax, N, D);

    int nt = N / BN;
    dual_gram_kernel<<<nt * nt, NTHREADS, 0, stream>>>(fkb, fgb, out, rowmax, N, D);

    finalize_kernel<<<2048, 256, 0, stream>>>(out, rowmax, N);
}

// Round 4
// 65.597 us; speedup vs baseline: 1.6132x; 1.6132x over previous
//
#include <hip/hip_runtime.h>
#include <hip/hip_bf16.h>
#include <cmath>

typedef __attribute__((ext_vector_type(8))) short short8;
typedef __attribute__((ext_vector_type(4))) float f32x4;

#define EPS_F 1e-7f
#define NEG_DIAG_F -10.0f

#define BM 128
#define BN 128
#define BK 64
#define NTHREADS 512
#define PADW 132            // f32 words per bounce row (2-way-free on row-store, 16B-aligned reads)
#define NPART 32            // column-tile groups in partial-max array

__device__ __forceinline__ void gload_lds16(const void* gptr, void* ldsptr) {
    __builtin_amdgcn_global_load_lds(
        (const __attribute__((address_space(1))) unsigned int*)gptr,
        (__attribute__((address_space(3))) unsigned int*)ldsptr,
        16, 0, 0);
}

// ---------------------------------------------------------------------------
// Kernel 1: row L2-normalize feat_k / feat_g (f32), cast to bf16.
// ---------------------------------------------------------------------------
__global__ void norm_cast_kernel(const float* __restrict__ fk, const float* __restrict__ fg,
                                 __hip_bfloat16* __restrict__ fkb, __hip_bfloat16* __restrict__ fgb,
                                 int N, int D) {
    int n = blockIdx.x;
    int t = threadIdx.x;
    float xk = fk[(size_t)n * D + t];
    float xg = fg[(size_t)n * D + t];
    float sk = xk * xk, sg = xg * xg;
#pragma unroll
    for (int off = 32; off > 0; off >>= 1) {
        sk += __shfl_xor(sk, off, 64);
        sg += __shfl_xor(sg, off, 64);
    }
    __shared__ float lsk[4], lsg[4];
    int w = t >> 6, l = t & 63;
    if (l == 0) { lsk[w] = sk; lsg[w] = sg; }
    __syncthreads();
    sk = lsk[0] + lsk[1] + lsk[2] + lsk[3];
    sg = lsg[0] + lsg[1] + lsg[2] + lsg[3];
    float rkv = 1.0f / (sqrtf(sk) + EPS_F);
    float rgv = 1.0f / (sqrtf(sg) + EPS_F);
    fkb[(size_t)n * D + t] = __float2bfloat16(xk * rkv);
    fgb[(size_t)n * D + t] = __float2bfloat16(xg * rgv);
}

// ---------------------------------------------------------------------------
// Kernel 2: upper-triangle dual Gram GEMM.  Block (by<=bx) computes its
// 128x128 s-tile, writes it AND the transposed tile (LDS bounce, float4
// coalesced), and emits per-block row/col partial maxes to P (no atomics).
// ---------------------------------------------------------------------------
__global__ __launch_bounds__(NTHREADS) void dual_gram_kernel(
    const __hip_bfloat16* __restrict__ fkb, const __hip_bfloat16* __restrict__ fgb,
    float* __restrict__ out, float* __restrict__ P, int N, int D) {

    __shared__ __align__(16) char smem[PADW * 128 * 4 + 1024];   // 67584 bounce/staging + 1KB lmax
    float* bounce = (float*)smem;
    int* lmax = (int*)(smem + PADW * 128 * 4);    // [0..127] row-max, [128..255] col-max

    int bx = blockIdx.x, by = blockIdx.y;
    if (by > bx) return;
    int r0 = by * BM, c0 = bx * BN;

    int t = threadIdx.x;
    int w = t >> 6, l = t & 63;
    int wr = w >> 2, wc = w & 3;   // 2 x 4 wave grid; wave tile = 64 rows x 32 cols
    int lr = l & 15, lg = l >> 4;

    char* lAk = smem;
    char* lBk = smem + 16384;
    char* lAg = smem + 32768;
    char* lBg = smem + 49152;

    f32x4 acck[4][2], accg[4][2];
    f32x4 zero = {0.f, 0.f, 0.f, 0.f};
#pragma unroll
    for (int m = 0; m < 4; ++m)
#pragma unroll
        for (int n = 0; n < 2; ++n) { acck[m][n] = zero; accg[m][n] = zero; }

    const size_t rowbytes = (size_t)D * 2;

    for (int k0 = 0; k0 < D; k0 += BK) {
#pragma unroll
        for (int c = 0; c < 2; ++c) {
            int o = (t + c * NTHREADS) * 16;           // linear byte offset in 16KB tile
            int row = o >> 7;                          // 128 B per LDS row (BK=64 bf16)
            int csw = (o & 127) ^ ((row & 7) << 4);    // inverse-swizzled source column
            size_t goffA = (size_t)(r0 + row) * rowbytes + (size_t)k0 * 2 + csw;
            size_t goffB = (size_t)(c0 + row) * rowbytes + (size_t)k0 * 2 + csw;
            int ldsoff = (w << 10) + (c << 13);        // wave-uniform dest base
            gload_lds16((const char*)fkb + goffA, lAk + ldsoff);
            gload_lds16((const char*)fkb + goffB, lBk + ldsoff);
            gload_lds16((const char*)fgb + goffA, lAg + ldsoff);
            gload_lds16((const char*)fgb + goffB, lBg + ldsoff);
        }
        __syncthreads();

#pragma unroll
        for (int kk = 0; kk < BK; kk += 32) {
            int kb = (kk + lg * 8) * 2;                // byte offset of this lane's 8 bf16
            short8 ak[4], ag[4], bk2[2], bg2[2];
#pragma unroll
            for (int m = 0; m < 4; ++m) {
                int row = wr * 64 + m * 16 + lr;
                int o = (row << 7) + kb;
                o ^= ((row & 7) << 4);                 // swizzled read
                ak[m] = *(const short8*)(lAk + o);
                ag[m] = *(const short8*)(lAg + o);
            }
#pragma unroll
            for (int n = 0; n < 2; ++n) {
                int row = wc * 32 + n * 16 + lr;
                int o = (row << 7) + kb;
                o ^= ((row & 7) << 4);
                bk2[n] = *(const short8*)(lBk + o);
                bg2[n] = *(const short8*)(lBg + o);
            }
#pragma unroll
            for (int m = 0; m < 4; ++m)
#pragma unroll
                for (int n = 0; n < 2; ++n) {
                    acck[m][n] = __builtin_amdgcn_mfma_f32_16x16x32_bf16(ak[m], bk2[n], acck[m][n], 0, 0, 0);
                    accg[m][n] = __builtin_amdgcn_mfma_f32_16x16x32_bf16(ag[m], bg2[n], accg[m][n], 0, 0, 0);
                }
        }
        __syncthreads();
    }

    // --- epilogue -----------------------------------------------------------
    if (t < 256) lmax[t] = 0;          // as-int encoding; all maxes are positive floats

    // compute s in place (acck becomes s)
    int lcol[2];                        // local column within tile
#pragma unroll
    for (int n = 0; n < 2; ++n) lcol[n] = wc * 32 + n * 16 + lr;

#pragma unroll
    for (int m = 0; m < 4; ++m)
#pragma unroll
        for (int j = 0; j < 4; ++j) {
            int lrow = wr * 64 + m * 16 + lg * 4 + j;     // C/D: row=(l>>4)*4+reg
#pragma unroll
            for (int n = 0; n < 2; ++n) {
                float dk = acck[m][n][j];
                float dg = accg[m][n][j];
                float s = (dk + 1.0f + EPS_F) * __builtin_amdgcn_rcpf(dg + 1.0f + EPS_F);
                if (r0 + lrow == c0 + lcol[n]) s = NEG_DIAG_F;
                acck[m][n][j] = s;
            }
        }
    __syncthreads();   // lmax init visible; staging reads done (loop barrier)

    // row partial maxes: per (m,j), max over this wave's 32 cols -> LDS
#pragma unroll
    for (int m = 0; m < 4; ++m)
#pragma unroll
        for (int j = 0; j < 4; ++j) {
            float pm = fmaxf(acck[m][0][j], acck[m][1][j]);
#pragma unroll
            for (int off = 1; off < 16; off <<= 1)
                pm = fmaxf(pm, __shfl_xor(pm, off, 64));
            if (lr == 0) atomicMax(&lmax[wr * 64 + m * 16 + lg * 4 + j], __float_as_int(pm));
        }
    // col partial maxes: per n, max over this wave's 64 rows -> LDS
#pragma unroll
    for (int n = 0; n < 2; ++n) {
        float cm = acck[0][n][0];
#pragma unroll
        for (int m = 0; m < 4; ++m)
#pragma unroll
            for (int j = 0; j < 4; ++j) cm = fmaxf(cm, acck[m][n][j]);
        cm = fmaxf(cm, __shfl_xor(cm, 16, 64));
        cm = fmaxf(cm, __shfl_xor(cm, 32, 64));
        if (l < 16) atomicMax(&lmax[128 + lcol[n]], __float_as_int(cm));
    }

    // bounce s -> LDS [row][col], pad 132
#pragma unroll
    for (int m = 0; m < 4; ++m)
#pragma unroll
        for (int n = 0; n < 2; ++n)
#pragma unroll
            for (int j = 0; j < 4; ++j)
                bounce[(wr * 64 + m * 16 + lg * 4 + j) * PADW + lcol[n]] = acck[m][n][j];
    __syncthreads();

    // direct tile write: coalesced float4 rows
#pragma unroll
    for (int i = 0; i < 8; ++i) {
        int r = (t >> 5) + 16 * i;
        int k = t & 31;
        f32x4 v = *(const f32x4*)(bounce + r * PADW + 4 * k);
        *(f32x4*)(out + (size_t)(r0 + r) * N + c0 + 4 * k) = v;
    }
    // partial-max writes (each P cell has exactly one writer)
    if (t < 128) {
        P[(size_t)(r0 + t) * NPART + bx] = __int_as_float(lmax[t]);
    } else if (t < 256 && by != bx) {
        P[(size_t)(c0 + t - 128) * NPART + by] = __int_as_float(lmax[t]);
    }

    if (by != bx) {
        __syncthreads();   // direct-pass reads done before overwrite
        // bounce s^T -> LDS [col][row]
#pragma unroll
        for (int m = 0; m < 4; ++m)
#pragma unroll
            for (int n = 0; n < 2; ++n)
#pragma unroll
                for (int j = 0; j < 4; ++j)
                    bounce[lcol[n] * PADW + (wr * 64 + m * 16 + lg * 4 + j)] = acck[m][n][j];
        __syncthreads();
        // transposed tile write: coalesced float4 rows of out panel (bx,by)
#pragma unroll
        for (int i = 0; i < 8; ++i) {
            int cc = (t >> 5) + 16 * i;
            int k = t & 31;
            f32x4 v = *(const f32x4*)(bounce + cc * PADW + 4 * k);
            *(f32x4*)(out + (size_t)(c0 + cc) * N + r0 + 4 * k) = v;
        }
    }
}

// ---------------------------------------------------------------------------
// Kernel 3: one block per row: m = max_j P[row][j]; out = exp(out - m).
// ---------------------------------------------------------------------------
__global__ void finalize_kernel(float* __restrict__ out, const float* __restrict__ P, int N) {
    int row = blockIdx.x;
    int t = threadIdx.x;            // 256
    float m = P[(size_t)row * NPART + (t & 31)];
#pragma unroll
    for (int off = 1; off < 32; off <<= 1)
        m = fmaxf(m, __shfl_xor(m, off, 64));
    float4* o4 = (float4*)(out + (size_t)row * N);
    int n4 = N >> 2;
    for (int i = t; i < n4; i += 256) {
        float4 v = o4[i];
        v.x = __expf(v.x - m);
        v.y = __expf(v.y - m);
        v.z = __expf(v.z - m);
        v.w = __expf(v.w - m);
        o4[i] = v;
    }
}

// ---------------------------------------------------------------------------
extern "C" void kernel_launch(void* const* d_in, const int* in_sizes, int n_in,
                              void* d_out, int out_size, void* d_ws, size_t ws_size,
                              hipStream_t stream) {
    const float* fk = (const float*)d_in[1];
    const float* fg = (const float*)d_in[2];
    float* out = (float*)d_out;

    int N = (int)llround(sqrt((double)out_size));   // 4096
    int D = in_sizes[1] / N;                        // 256

    char* ws = (char*)d_ws;
    float* P = (float*)ws;                                          // 4096*32*4 = 512 KB
    __hip_bfloat16* fkb = (__hip_bfloat16*)(ws + (size_t)N * NPART * 4);
    __hip_bfloat16* fgb = (__hip_bfloat16*)(ws + (size_t)N * NPART * 4 + (size_t)N * D * 2);

    norm_cast_kernel<<<N, D, 0, stream>>>(fk, fg, fkb, fgb, N, D);

    int nt = N / BN;
    dual_gram_kernel<<<dim3(nt, nt), NTHREADS, 0, stream>>>(fkb, fgb, out, P, N, D);

    finalize_kernel<<<N, 256, 0, stream>>>(out, P, N);
}